// Round 15
// baseline (2954.115 us; speedup 1.0000x reference)
//
#include <hip/hip_runtime.h>
#include <cstdint>

#define NCAND 1360
#define KPRE 512
#define BOXLIM 100
#define BIMG 8
#define CCH 16

// ---------- helpers ----------

static __device__ __forceinline__ unsigned int ford(float f){
  unsigned int u = __float_as_uint(f);
  return (u & 0x80000000u) ? ~u : (u | 0x80000000u);
}

static __device__ __forceinline__ float bil(float f00, float f01, float f10, float f11,
                                            float oy, float ly, float ox, float lx, bool oob){
  float t1 = __fmul_rn(__fmul_rn(f00, oy), ox);
  float t2 = __fmul_rn(__fmul_rn(f01, oy), lx);
  float t3 = __fmul_rn(__fmul_rn(f10, ly), ox);
  float t4 = __fmul_rn(__fmul_rn(f11, ly), lx);
  float v = __fadd_rn(__fadd_rn(__fadd_rn(t1, t2), t3), t4);
  return oob ? 0.0f : v;
}

// ---------- K0: transpose conv1 weights to wT[c][9][oc] (lane-coalesced) ----------

__global__ void k_wt(const float* __restrict__ w1, float* __restrict__ wT){
  int t = blockIdx.x*256 + threadIdx.x;
  if (t >= 64*480*9) return;
  int oc = t & 63; int m = t >> 6; int k = m % 9; int c = m / 9;
  wT[t] = w1[((size_t)oc*480 + c)*9 + k];
}

// ---------- K1: YOLOX decode ----------

__global__ void k_decode(const float* __restrict__ p0, const float* __restrict__ p1,
                         const float* __restrict__ p2, const float* __restrict__ p3,
                         float* __restrict__ dbox, float* __restrict__ dscore,
                         int* __restrict__ dlabel, unsigned long long* __restrict__ dkey){
  int t = blockIdx.x*256 + threadIdx.x;
  if (t >= BIMG*NCAND) return;
  int b = t / NCAND, n = t % NCAND;
  const float* p; int H, s, base;
  if (n < 1024)      { p = p0; H = 32; s = 8;  base = 0;    }
  else if (n < 1280) { p = p1; H = 16; s = 16; base = 1024; }
  else if (n < 1344) { p = p2; H = 8;  s = 32; base = 1280; }
  else               { p = p3; H = 4;  s = 64; base = 1344; }
  int loc = n - base; int hw = H*H; int i = loc / H, j = loc % H;
  const float* q = p + (size_t)b*8*hw + loc;
  float q0 = q[0],    q1 = q[hw],   q2 = q[2*hw], q3 = q[3*hw];
  float q4 = q[4*hw], q5 = q[5*hw], q6 = q[6*hw], q7 = q[7*hw];
  float sf = (float)s;
  float cx = __fmul_rn(__fadd_rn(__fadd_rn(q0, 0.5f), (float)j), sf);
  float cy = __fmul_rn(__fadd_rn(__fadd_rn(q1, 0.5f), (float)i), sf);
  float bw = __fmul_rn(expf(q2), sf);
  float bh = __fmul_rn(expf(q3), sf);
  float hx = __fmul_rn(bw, 0.5f), hy = __fmul_rn(bh, 0.5f);
  dbox[(size_t)t*4+0] = __fsub_rn(cx, hx);
  dbox[(size_t)t*4+1] = __fsub_rn(cy, hy);
  dbox[(size_t)t*4+2] = __fadd_rn(cx, hx);
  dbox[(size_t)t*4+3] = __fadd_rn(cy, hy);
  float sc = __fdiv_rn(1.0f, __fadd_rn(1.0f, expf(-q4)));
  dscore[t] = sc;
  int lab = 0; float mx = q5;
  if (q6 > mx){ mx = q6; lab = 1; }
  if (q7 > mx){ lab = 2; }
  dlabel[t] = lab;
  unsigned int od = (sc > 0.5f) ? ford(sc) : 0x007FFFFFu;  // 0x007FFFFF == ord(-inf)
  dkey[t] = ((unsigned long long)od << 32) | (unsigned long long)(0xFFFFFFFFu - (unsigned)n);
}

// ---------- K2: per-image bitonic top-512 ----------

__global__ __launch_bounds__(1024) void k_sort(const unsigned long long* __restrict__ dkey,
    const float* __restrict__ dbox, const float* __restrict__ dscore, const int* __restrict__ dlabel,
    float* __restrict__ tbox, float* __restrict__ tscore, int* __restrict__ tlabel, int* __restrict__ tvalid){
  __shared__ unsigned long long sk[2048];
  int b = blockIdx.x, tid = threadIdx.x;
  for (int e = tid; e < 2048; e += 1024)
    sk[e] = (e < NCAND) ? dkey[b*NCAND + e] : 0ull;
  __syncthreads();
  for (int k = 2; k <= 2048; k <<= 1){
    for (int j = k >> 1; j > 0; j >>= 1){
      for (int e = tid; e < 2048; e += 1024){
        int ixj = e ^ j;
        if (ixj > e){
          bool up = ((e & k) == 0);
          unsigned long long a = sk[e], c = sk[ixj];
          if (up ? (a < c) : (a > c)){ sk[e] = c; sk[ixj] = a; }  // descending overall
        }
      }
      __syncthreads();
    }
  }
  if (tid < KPRE){
    unsigned long long key = sk[tid];
    int n = (int)(0xFFFFFFFFu - (unsigned)(key & 0xFFFFFFFFull));
    int valid = ((unsigned)(key >> 32) != 0x007FFFFFu) ? 1 : 0;
    int src = b*NCAND + n;
    int dst = b*KPRE + tid;
    tbox[dst*4+0] = dbox[(size_t)src*4+0];
    tbox[dst*4+1] = dbox[(size_t)src*4+1];
    tbox[dst*4+2] = dbox[(size_t)src*4+2];
    tbox[dst*4+3] = dbox[(size_t)src*4+3];
    tscore[dst] = dscore[src];
    tlabel[dst] = dlabel[src];
    tvalid[dst] = valid;
  }
}

// ---------- K3: per-image greedy NMS + compaction ----------

__global__ __launch_bounds__(256) void k_nms(const float* __restrict__ tbox, const float* __restrict__ tscore,
    const int* __restrict__ tlabel, const int* __restrict__ tvalid,
    float* __restrict__ sbox, float* __restrict__ sscore, int* __restrict__ slabel, int* __restrict__ svalid){
  __shared__ float X0[KPRE], Y0[KPRE], X1[KPRE], Y1[KPRE], AR[KPRE];
  __shared__ unsigned long long sup[KPRE][8];
  __shared__ unsigned long long keepw[8];
  __shared__ unsigned char vf[KPRE];
  int b = blockIdx.x, tid = threadIdx.x;
  for (int k = tid; k < KPRE; k += 256){
    int src = b*KPRE + k;
    float off = (float)tlabel[src] * 1024.0f;  // 4*PATCH, exact
    float x0 = __fadd_rn(tbox[src*4+0], off), y0 = __fadd_rn(tbox[src*4+1], off);
    float x1 = __fadd_rn(tbox[src*4+2], off), y1 = __fadd_rn(tbox[src*4+3], off);
    X0[k] = x0; Y0[k] = y0; X1[k] = x1; Y1[k] = y1;
    AR[k] = __fmul_rn(fmaxf(__fsub_rn(x1, x0), 0.0f), fmaxf(__fsub_rn(y1, y0), 0.0f));
    vf[k] = (unsigned char)tvalid[src];
  }
  __syncthreads();
  for (int t = tid; t < KPRE*8; t += 256){
    int i = t >> 3, w = t & 7;
    unsigned long long m = 0;
    float ax0 = X0[i], ay0 = Y0[i], ax1 = X1[i], ay1 = Y1[i], aar = AR[i];
    for (int bit = 0; bit < 64; ++bit){
      int j = (w << 6) + bit;
      if (j > i){
        float ltx = fmaxf(ax0, X0[j]), lty = fmaxf(ay0, Y0[j]);
        float rbx = fminf(ax1, X1[j]), rby = fminf(ay1, Y1[j]);
        float ww = fmaxf(__fsub_rn(rbx, ltx), 0.0f), hh = fmaxf(__fsub_rn(rby, lty), 0.0f);
        float inter = __fmul_rn(ww, hh);
        float uni = __fsub_rn(__fadd_rn(aar, AR[j]), inter);
        float iou = __fdiv_rn(inter, fmaxf(uni, 1e-9f));
        if (iou > 0.5f) m |= (1ull << bit);
      }
    }
    sup[i][w] = m;
  }
  __syncthreads();
  if (tid < 64){
    int lane = tid;
    unsigned long long keep = 0;
    if (lane < 8){
      for (int bit = 0; bit < 64; ++bit)
        if (vf[(lane << 6) + bit]) keep |= (1ull << bit);
    }
    for (int i = 0; i < KPRE; ++i){
      unsigned long long kw = __shfl(keep, i >> 6);
      if ((kw >> (i & 63)) & 1ull){
        if (lane < 8) keep &= ~sup[i][lane];
      }
    }
    if (lane < 8) keepw[lane] = keep;
  }
  __syncthreads();
  if (tid < BOXLIM){
    int d = b*BOXLIM + tid;
    sscore[d] = 0.0f; slabel[d] = 0; svalid[d] = 0;
    sbox[d*4+0] = 0.0f; sbox[d*4+1] = 0.0f; sbox[d*4+2] = 0.0f; sbox[d*4+3] = 0.0f;
  }
  __syncthreads();
  int wp[8]; int sum = 0;
#pragma unroll
  for (int w = 0; w < 8; ++w){ wp[w] = sum; sum += __popcll(keepw[w]); }
  for (int r0 = tid; r0 < KPRE; r0 += 256){
    int wi = r0 >> 6, bi = r0 & 63;
    if ((keepw[wi] >> bi) & 1ull){
      unsigned long long below = bi ? (keepw[wi] & ((~0ull) >> (64 - bi))) : 0ull;
      int rank = wp[wi] + __popcll(below);
      if (rank < BOXLIM){
        int src = b*KPRE + r0, d = b*BOXLIM + rank;
        sbox[d*4+0] = tbox[src*4+0]; sbox[d*4+1] = tbox[src*4+1];
        sbox[d*4+2] = tbox[src*4+2]; sbox[d*4+3] = tbox[src*4+3];
        sscore[d] = tscore[src]; slabel[d] = tlabel[src]; svalid[d] = 1;
      }
    }
  }
}

// ---------- K3b: compact valid ROI indices into a dense list ----------

__global__ __launch_bounds__(1024) void k_compact(const int* __restrict__ svalid,
                                                  int* __restrict__ rlist, int* __restrict__ nvalid){
  __shared__ int wcnt[16], woff[16];
  int tid = threadIdx.x;
  int w = tid >> 6, lane = tid & 63;
  int flag = (tid < BIMG*BOXLIM) ? svalid[tid] : 0;
  unsigned long long mask = __ballot(flag != 0);
  if (lane == 0) wcnt[w] = __popcll(mask);
  __syncthreads();
  if (tid == 0){
    int run = 0;
    for (int i = 0; i < 16; ++i){ woff[i] = run; run += wcnt[i]; }
    *nvalid = run;
  }
  __syncthreads();
  if (flag){
    unsigned long long below = lane ? (mask & ((~0ull) >> (64 - lane))) : 0ull;
    rlist[woff[w] + __popcll(below)] = tid;
  }
}

// ---------- K4: merge mask feats to channels-last [8][64][64][480] ----------

__global__ void k_merge(const float* __restrict__ m0, const float* __restrict__ m1,
                        const float* __restrict__ m2, const float* __restrict__ m3,
                        float* __restrict__ merged){
  int t = blockIdx.x*256 + threadIdx.x;
  if (t >= 8*64*64*480) return;
  int c = t % 480; int xy = t / 480;
  int x = xy & 63; int y = (xy >> 6) & 63; int b = xy >> 12;
  float v;
  if (c < 32)       v = m0[(((size_t)b*32  +  c      )*64 +  y      )*64 +  x      ];
  else if (c < 96)  v = m1[(((size_t)b*64  + (c - 32))*32 + (y >> 1))*32 + (x >> 1)];
  else if (c < 224) v = m2[(((size_t)b*128 + (c - 96))*16 + (y >> 2))*16 + (x >> 2)];
  else              v = m3[(((size_t)b*256 + (c - 224))*8 + (y >> 3))*8  + (x >> 3)];
  merged[t] = v;
}

// ---------- K5: fused RoIAlign + conv3x3(480->64) + ReLU + conv1x1(64->1) ----------
// R14 arithmetic verbatim, restructured as a DOUBLE-BUFFERED pipeline:
// model says the invariant ~3.5k cyc/chunk is ~60% VALU issue + ~40% stall
// at the 2 per-chunk barriers (2nd barrier drains the staging global loads,
// vmcnt 200-900 cyc, and with 1 block/CU nothing hides it — R14 proved a 2nd
// resident block never materializes). Two tile+weight buffers (LDS 109 KB):
// per chunk, issue chunk-i+1 globals into registers -> compute 16 cc from
// buf[cur] (~2.3k cyc covers the latency) -> bil + write buf[nxt] -> ONE
// barrier -> swap. Same bil expressions on same inputs, same cc 0..479 /
// k 0..8 FMA chains, same epilogue tree -> logits bit-identical.

__global__ __launch_bounds__(1024, 4) void k_maskhead(const float* __restrict__ merged, const float* __restrict__ wT,
    const float* __restrict__ b1, const float* __restrict__ w2, const float* __restrict__ b2,
    const float* __restrict__ sbox, const int* __restrict__ rlist, const int* __restrict__ nvalid,
    float* __restrict__ lm){
  __shared__ float tile[2][CCH*288];              // 2 x 18 KB, rows 0/17 zero halo
  __shared__ __align__(16) float wlds[2][CCH*576];// 2 x 36 KB
  __shared__ float outp[256];
  int tid = threadIdx.x;
  int oc = tid & 63, row = tid >> 6;      // compute mapping: one row per wave
  int pix = tid & 255, qq = tid >> 8;     // fill mapping: 4 channel-quarters x 256 px
  int pi = pix >> 4, pj = pix & 15;
  float b1v = b1[oc], w2v = w2[oc], b2v = b2[0];
  int NV = *nvalid;

  // zero halo rows of BOTH buffers once (writers only touch padded rows 1..16)
  for (int i = tid; i < 2*CCH*32; i += 1024){
    int bsel = i >> 9;                  // CCH*32 == 512
    int ii = i & 511;
    int cc = ii >> 5, k = ii & 31;
    tile[bsel][cc*288 + ((k < 16) ? 0 : 272) + (k & 15)] = 0.0f;
  }
  __syncthreads();

  for (int it = blockIdx.x; it < NV; it += gridDim.x){
    int r = rlist[it];
    int b = r / 100;
    float bx0 = sbox[r*4+0], by0 = sbox[r*4+1], bx1 = sbox[r*4+2], by1 = sbox[r*4+3];
    float rw = fmaxf(__fsub_rn(bx1, bx0), 1.0f), rh = fmaxf(__fsub_rn(by1, by0), 1.0f);
    float xx = __fadd_rn(bx0, __fdiv_rn(__fmul_rn(__fadd_rn((float)pj, 0.5f), rw), 16.0f));
    float yy = __fadd_rn(by0, __fdiv_rn(__fmul_rn(__fadd_rn(( float)pi, 0.5f), rh), 16.0f));
    bool oob = (yy < -1.0f) || (yy > 64.0f) || (xx < -1.0f) || (xx > 64.0f);
    float yc = fminf(fmaxf(yy, 0.0f), 63.0f), xc = fminf(fmaxf(xx, 0.0f), 63.0f);
    int yi0 = (int)floorf(yc), xi0 = (int)floorf(xc);
    int yi1 = min(yi0 + 1, 63), xi1 = min(xi0 + 1, 63);
    float ly = __fsub_rn(yc, (float)yi0), lx = __fsub_rn(xc, (float)xi0);
    float oy = __fsub_rn(1.0f, ly), ox = __fsub_rn(1.0f, lx);
    size_t ib = (size_t)b*64*64*480;
    const float* p00 = merged + ib + (size_t)(yi0*64 + xi0)*480 + qq*4;
    const float* p01 = merged + ib + (size_t)(yi0*64 + xi1)*480 + qq*4;
    const float* p10 = merged + ib + (size_t)(yi1*64 + xi0)*480 + qq*4;
    const float* p11 = merged + ib + (size_t)(yi1*64 + xi1)*480 + qq*4;
    int wpos = (pi + 1)*16 + pj;          // padded interior write position
    float acc[16];
#pragma unroll
    for (int j = 0; j < 16; ++j) acc[j] = 0.0f;

    // ---- prologue: stage chunk 0 into buffer 0 ----
    {
      float4 f00 = *(const float4*)(p00);
      float4 f01 = *(const float4*)(p01);
      float4 f10 = *(const float4*)(p10);
      float4 f11 = *(const float4*)(p11);
      int c0 = qq*4;
      tile[0][(c0+0)*288 + wpos] = bil(f00.x, f01.x, f10.x, f11.x, oy, ly, ox, lx, oob);
      tile[0][(c0+1)*288 + wpos] = bil(f00.y, f01.y, f10.y, f11.y, oy, ly, ox, lx, oob);
      tile[0][(c0+2)*288 + wpos] = bil(f00.z, f01.z, f10.z, f11.z, oy, ly, ox, lx, oob);
      tile[0][(c0+3)*288 + wpos] = bil(f00.w, f01.w, f10.w, f11.w, oy, ly, ox, lx, oob);
      const float4* src = (const float4*)(wT);
      float4* dst = (float4*)wlds[0];
#pragma unroll
      for (int u = 0; u < 3; ++u){
        int i = tid + u*1024;
        if (i < CCH*144) dst[i] = src[i];
      }
    }
    __syncthreads();

    int cur = 0;
    for (int cb = 0; cb < 480; cb += CCH){
      bool more = (cb + CCH) < 480;
      // ---- issue prefetch for chunk i+1 (in-flight during compute) ----
      float4 g00, g01, g10, g11;
      float4 wr[3];
      if (more){
        g00 = *(const float4*)(p00 + cb + CCH);
        g01 = *(const float4*)(p01 + cb + CCH);
        g10 = *(const float4*)(p10 + cb + CCH);
        g11 = *(const float4*)(p11 + cb + CCH);
        const float4* src = (const float4*)(wT + (size_t)(cb + CCH)*576);
#pragma unroll
        for (int u = 0; u < 3; ++u){
          int i = tid + u*1024;
          if (i < CCH*144) wr[u] = src[i];
        }
      }
      // ---- compute 16 channels from buf[cur] ----
      const float* tb = tile[cur];
      const float* wb = wlds[cur];
#pragma unroll 1
      for (int cc = 0; cc < CCH; ++cc){
        const float* wo = wb + cc*576 + oc;         // lane-stride 4B: conflict-free
        float W0 = wo[0],   W1 = wo[64],  W2 = wo[128];
        float W3 = wo[192], W4 = wo[256], W5 = wo[320];
        float W6 = wo[384], W7 = wo[448], W8 = wo[512];
        const float4* ta = (const float4*)(tb + cc*288 + row*16);
        float4 a0 = ta[0], a1 = ta[1], a2 = ta[2], a3 = ta[3];
        float4 b0 = ta[4], b1q = ta[5], b2q = ta[6], b3 = ta[7];
        float4 c0 = ta[8], c1 = ta[9], c2 = ta[10], c3 = ta[11];
        float A[16] = {a0.x,a0.y,a0.z,a0.w, a1.x,a1.y,a1.z,a1.w,
                       a2.x,a2.y,a2.z,a2.w, a3.x,a3.y,a3.z,a3.w};
        float B[16] = {b0.x,b0.y,b0.z,b0.w, b1q.x,b1q.y,b1q.z,b1q.w,
                       b2q.x,b2q.y,b2q.z,b2q.w, b3.x,b3.y,b3.z,b3.w};
        float C[16] = {c0.x,c0.y,c0.z,c0.w, c1.x,c1.y,c1.z,c1.w,
                       c2.x,c2.y,c2.z,c2.w, c3.x,c3.y,c3.z,c3.w};
#pragma unroll
        for (int j = 0; j < 16; ++j){
          float a = acc[j];
          if (j > 0)  a = fmaf(A[j-1], W0, a);
                      a = fmaf(A[j],   W1, a);
          if (j < 15) a = fmaf(A[j+1], W2, a);
          if (j > 0)  a = fmaf(B[j-1], W3, a);
                      a = fmaf(B[j],   W4, a);
          if (j < 15) a = fmaf(B[j+1], W5, a);
          if (j > 0)  a = fmaf(C[j-1], W6, a);
                      a = fmaf(C[j],   W7, a);
          if (j < 15) a = fmaf(C[j+1], W8, a);
          acc[j] = a;
        }
      }
      // ---- write prefetched chunk into buf[nxt]; ONE barrier; swap ----
      if (more){
        int nxt = cur ^ 1;
        int c0 = qq*4;
        tile[nxt][(c0+0)*288 + wpos] = bil(g00.x, g01.x, g10.x, g11.x, oy, ly, ox, lx, oob);
        tile[nxt][(c0+1)*288 + wpos] = bil(g00.y, g01.y, g10.y, g11.y, oy, ly, ox, lx, oob);
        tile[nxt][(c0+2)*288 + wpos] = bil(g00.z, g01.z, g10.z, g11.z, oy, ly, ox, lx, oob);
        tile[nxt][(c0+3)*288 + wpos] = bil(g00.w, g01.w, g10.w, g11.w, oy, ly, ox, lx, oob);
        float4* dst = (float4*)wlds[nxt];
#pragma unroll
        for (int u = 0; u < 3; ++u){
          int i = tid + u*1024;
          if (i < CCH*144) dst[i] = wr[u];
        }
      }
      __syncthreads();
      cur ^= 1;
    }
#pragma unroll
    for (int j = 0; j < 16; ++j){
      float hv = fmaxf(__fadd_rn(acc[j], b1v), 0.0f);
      float v = __fmul_rn(hv, w2v);
      v += __shfl_down(v, 32);
      v += __shfl_down(v, 16);
      v += __shfl_down(v, 8);
      v += __shfl_down(v, 4);
      v += __shfl_down(v, 2);
      v += __shfl_down(v, 1);
      if (oc == 0) outp[row*16 + j] = __fadd_rn(v, b2v);
    }
    __syncthreads();
    if (tid < 256) lm[(size_t)r*256 + tid] = outp[tid];
    __syncthreads();
  }
}

// ---------- K6: paste masks + final outputs (mask plane pre-zeroed by memset) ----------

__global__ __launch_bounds__(256) void k_paste(const float* __restrict__ lm, const float* __restrict__ sbox,
    const float* __restrict__ sscore, const int* __restrict__ slabel, const int* __restrict__ svalid,
    float* __restrict__ out0, float* __restrict__ out1, float* __restrict__ out2,
    float* __restrict__ out3, float* __restrict__ out4){
  int r = blockIdx.x, tid = threadIdx.x;
  float* om = out3 + (size_t)r*65536;
  int valid = svalid[r];
  __shared__ unsigned char lmb[256];
  __shared__ int symap[256];
  __shared__ int anyf;
  if (tid == 0) anyf = 0;
  int x0i = 0, y0i = 0, x1i = 0, y1i = 0; int sxv = 0; bool insx = false;
  if (valid){
    float fx0 = sbox[r*4+0], fy0 = sbox[r*4+1], fx1 = sbox[r*4+2], fy1 = sbox[r*4+3];
    x0i = min(max((int)fx0, 0), 255); y0i = min(max((int)fy0, 0), 255);
    x1i = min(max((int)fx1, 0), 255); y1i = min(max((int)fy1, 0), 255);
    int hh = y1i - y0i + 1, wwd = x1i - x0i + 1;
    float logit = lm[(size_t)r*256 + tid];
    float sg = __fdiv_rn(1.0f, __fadd_rn(1.0f, expf(-logit)));
    lmb[tid] = (sg > 0.5f) ? (unsigned char)1 : (unsigned char)0;
    int dy = tid - y0i; symap[tid] = (dy >= 0) ? min((dy*16)/hh, 15) : 0;
    int dx = tid - x0i; sxv = (dx >= 0) ? min((dx*16)/wwd, 15) : 0;
    insx = (tid >= x0i) && (tid <= x1i);
  }
  __syncthreads();
  bool any = false;
  if (valid){
    for (int yy = y0i; yy <= y1i; ++yy){
      int sy = symap[yy];
      bool mm = insx && (lmb[(sy << 4) + sxv] != 0);
      any = any || mm;
      om[yy*256 + tid] = mm ? 1.0f : 0.0f;
    }
  }
  if (any) atomicOr(&anyf, 1);
  __syncthreads();
  if (tid == 0){
    int vout = valid && (anyf != 0);
    out0[r] = vout ? sscore[r] : 0.0f;
    out1[r*4+0] = vout ? sbox[r*4+0] : 0.0f;
    out1[r*4+1] = vout ? sbox[r*4+1] : 0.0f;
    out1[r*4+2] = vout ? sbox[r*4+2] : 0.0f;
    out1[r*4+3] = vout ? sbox[r*4+3] : 0.0f;
    out2[r] = vout ? (float)slabel[r] : 0.0f;
    out4[r] = vout ? 1.0f : 0.0f;
  }
}

// ---------- host ----------

extern "C" void kernel_launch(void* const* d_in, const int* in_sizes, int n_in,
                              void* d_out, int out_size, void* d_ws, size_t ws_size,
                              hipStream_t stream){
  const float* p0 = (const float*)d_in[0];
  const float* p1 = (const float*)d_in[1];
  const float* p2 = (const float*)d_in[2];
  const float* p3 = (const float*)d_in[3];
  const float* m0 = (const float*)d_in[4];
  const float* m1 = (const float*)d_in[5];
  const float* m2 = (const float*)d_in[6];
  const float* m3 = (const float*)d_in[7];
  const float* w1 = (const float*)d_in[8];
  const float* b1 = (const float*)d_in[9];
  const float* w2 = (const float*)d_in[10];
  const float* b2 = (const float*)d_in[11];
  (void)in_sizes; (void)n_in; (void)out_size; (void)ws_size;

  char* ws = (char*)d_ws;
  size_t off = 0;
  auto A = [&](size_t n) -> char* {
    char* p = ws + off;
    off = (off + n + 255) & ~(size_t)255;
    return p;
  };
  float* dbox   = (float*)A((size_t)BIMG*NCAND*4*4);
  float* dscore = (float*)A((size_t)BIMG*NCAND*4);
  int*   dlabel = (int*)A((size_t)BIMG*NCAND*4);
  unsigned long long* dkey = (unsigned long long*)A((size_t)BIMG*NCAND*8);
  float* tbox   = (float*)A((size_t)BIMG*KPRE*4*4);
  float* tscore = (float*)A((size_t)BIMG*KPRE*4);
  int*   tlabel = (int*)A((size_t)BIMG*KPRE*4);
  int*   tvalid = (int*)A((size_t)BIMG*KPRE*4);
  float* sbox   = (float*)A((size_t)BIMG*BOXLIM*4*4);
  float* sscore = (float*)A((size_t)BIMG*BOXLIM*4);
  int*   slabel = (int*)A((size_t)BIMG*BOXLIM*4);
  int*   svalid = (int*)A((size_t)BIMG*BOXLIM*4);
  int*   rlist  = (int*)A((size_t)BIMG*BOXLIM*4);
  int*   nvalid = (int*)A(4);
  float* wT     = (float*)A((size_t)64*480*9*4);
  float* lm     = (float*)A((size_t)800*256*4);
  float* merged = (float*)A((size_t)8*64*64*480*4);

  float* out0 = (float*)d_out;           // scores  [8,100]
  float* out1 = out0 + 800;              // boxes   [8,100,4]
  float* out2 = out1 + 3200;             // labels  [8,100]
  float* out3 = out2 + 800;              // masks   [8,100,256,256]
  float* out4 = out3 + (size_t)8*100*256*256;  // valid [8,100]

  hipMemsetAsync(out3, 0, (size_t)8*100*256*256*4, stream);

  hipLaunchKernelGGL(k_wt,      dim3(1080),  dim3(256),  0, stream, w1, wT);
  hipLaunchKernelGGL(k_decode,  dim3(43),    dim3(256),  0, stream, p0, p1, p2, p3, dbox, dscore, dlabel, dkey);
  hipLaunchKernelGGL(k_merge,   dim3(61440), dim3(256),  0, stream, m0, m1, m2, m3, merged);
  hipLaunchKernelGGL(k_sort,    dim3(8),     dim3(1024), 0, stream, dkey, dbox, dscore, dlabel,
                     tbox, tscore, tlabel, tvalid);
  hipLaunchKernelGGL(k_nms,     dim3(8),     dim3(256),  0, stream, tbox, tscore, tlabel, tvalid,
                     sbox, sscore, slabel, svalid);
  hipLaunchKernelGGL(k_compact, dim3(1),     dim3(1024), 0, stream, svalid, rlist, nvalid);
  hipLaunchKernelGGL(k_maskhead, dim3(256),  dim3(1024), 0, stream, merged, wT, b1, w2, b2,
                     sbox, rlist, nvalid, lm);
  hipLaunchKernelGGL(k_paste,   dim3(800),   dim3(256),  0, stream, lm, sbox, sscore, slabel, svalid,
                     out0, out1, out2, out3, out4);
}

// Round 16
// 1882.163 us; speedup vs baseline: 1.5695x; 1.5695x over previous
//
#include <hip/hip_runtime.h>
#include <cstdint>

#define NCAND 1360
#define KPRE 512
#define BOXLIM 100
#define BIMG 8
#define CCH 16

typedef float float2v __attribute__((ext_vector_type(2)));

// ---------- helpers ----------

static __device__ __forceinline__ unsigned int ford(float f){
  unsigned int u = __float_as_uint(f);
  return (u & 0x80000000u) ? ~u : (u | 0x80000000u);
}

static __device__ __forceinline__ float bil(float f00, float f01, float f10, float f11,
                                            float oy, float ly, float ox, float lx, bool oob){
  float t1 = __fmul_rn(__fmul_rn(f00, oy), ox);
  float t2 = __fmul_rn(__fmul_rn(f01, oy), lx);
  float t3 = __fmul_rn(__fmul_rn(f10, ly), ox);
  float t4 = __fmul_rn(__fmul_rn(f11, ly), lx);
  float v = __fadd_rn(__fadd_rn(__fadd_rn(t1, t2), t3), t4);
  return oob ? 0.0f : v;
}

// ---------- K0: conv1 weights to channel-pair-interleaved wT[cpair][k][oc][2] ----------

__global__ void k_wt(const float* __restrict__ w1, float* __restrict__ wT){
  int t = blockIdx.x*256 + threadIdx.x;
  if (t >= 64*480*9) return;
  int oc = t & 63; int m = t >> 6; int k = m % 9; int c = m / 9;
  wT[(((size_t)(c >> 1)*9 + k)*64 + oc)*2 + (c & 1)] = w1[((size_t)oc*480 + c)*9 + k];
}

// ---------- K1: YOLOX decode ----------

__global__ void k_decode(const float* __restrict__ p0, const float* __restrict__ p1,
                         const float* __restrict__ p2, const float* __restrict__ p3,
                         float* __restrict__ dbox, float* __restrict__ dscore,
                         int* __restrict__ dlabel, unsigned long long* __restrict__ dkey){
  int t = blockIdx.x*256 + threadIdx.x;
  if (t >= BIMG*NCAND) return;
  int b = t / NCAND, n = t % NCAND;
  const float* p; int H, s, base;
  if (n < 1024)      { p = p0; H = 32; s = 8;  base = 0;    }
  else if (n < 1280) { p = p1; H = 16; s = 16; base = 1024; }
  else if (n < 1344) { p = p2; H = 8;  s = 32; base = 1280; }
  else               { p = p3; H = 4;  s = 64; base = 1344; }
  int loc = n - base; int hw = H*H; int i = loc / H, j = loc % H;
  const float* q = p + (size_t)b*8*hw + loc;
  float q0 = q[0],    q1 = q[hw],   q2 = q[2*hw], q3 = q[3*hw];
  float q4 = q[4*hw], q5 = q[5*hw], q6 = q[6*hw], q7 = q[7*hw];
  float sf = (float)s;
  float cx = __fmul_rn(__fadd_rn(__fadd_rn(q0, 0.5f), (float)j), sf);
  float cy = __fmul_rn(__fadd_rn(__fadd_rn(q1, 0.5f), (float)i), sf);
  float bw = __fmul_rn(expf(q2), sf);
  float bh = __fmul_rn(expf(q3), sf);
  float hx = __fmul_rn(bw, 0.5f), hy = __fmul_rn(bh, 0.5f);
  dbox[(size_t)t*4+0] = __fsub_rn(cx, hx);
  dbox[(size_t)t*4+1] = __fsub_rn(cy, hy);
  dbox[(size_t)t*4+2] = __fadd_rn(cx, hx);
  dbox[(size_t)t*4+3] = __fadd_rn(cy, hy);
  float sc = __fdiv_rn(1.0f, __fadd_rn(1.0f, expf(-q4)));
  dscore[t] = sc;
  int lab = 0; float mx = q5;
  if (q6 > mx){ mx = q6; lab = 1; }
  if (q7 > mx){ lab = 2; }
  dlabel[t] = lab;
  unsigned int od = (sc > 0.5f) ? ford(sc) : 0x007FFFFFu;  // 0x007FFFFF == ord(-inf)
  dkey[t] = ((unsigned long long)od << 32) | (unsigned long long)(0xFFFFFFFFu - (unsigned)n);
}

// ---------- K2: per-image bitonic top-512 ----------

__global__ __launch_bounds__(1024) void k_sort(const unsigned long long* __restrict__ dkey,
    const float* __restrict__ dbox, const float* __restrict__ dscore, const int* __restrict__ dlabel,
    float* __restrict__ tbox, float* __restrict__ tscore, int* __restrict__ tlabel, int* __restrict__ tvalid){
  __shared__ unsigned long long sk[2048];
  int b = blockIdx.x, tid = threadIdx.x;
  for (int e = tid; e < 2048; e += 1024)
    sk[e] = (e < NCAND) ? dkey[b*NCAND + e] : 0ull;
  __syncthreads();
  for (int k = 2; k <= 2048; k <<= 1){
    for (int j = k >> 1; j > 0; j >>= 1){
      for (int e = tid; e < 2048; e += 1024){
        int ixj = e ^ j;
        if (ixj > e){
          bool up = ((e & k) == 0);
          unsigned long long a = sk[e], c = sk[ixj];
          if (up ? (a < c) : (a > c)){ sk[e] = c; sk[ixj] = a; }  // descending overall
        }
      }
      __syncthreads();
    }
  }
  if (tid < KPRE){
    unsigned long long key = sk[tid];
    int n = (int)(0xFFFFFFFFu - (unsigned)(key & 0xFFFFFFFFull));
    int valid = ((unsigned)(key >> 32) != 0x007FFFFFu) ? 1 : 0;
    int src = b*NCAND + n;
    int dst = b*KPRE + tid;
    tbox[dst*4+0] = dbox[(size_t)src*4+0];
    tbox[dst*4+1] = dbox[(size_t)src*4+1];
    tbox[dst*4+2] = dbox[(size_t)src*4+2];
    tbox[dst*4+3] = dbox[(size_t)src*4+3];
    tscore[dst] = dscore[src];
    tlabel[dst] = dlabel[src];
    tvalid[dst] = valid;
  }
}

// ---------- K3: per-image greedy NMS + compaction ----------

__global__ __launch_bounds__(256) void k_nms(const float* __restrict__ tbox, const float* __restrict__ tscore,
    const int* __restrict__ tlabel, const int* __restrict__ tvalid,
    float* __restrict__ sbox, float* __restrict__ sscore, int* __restrict__ slabel, int* __restrict__ svalid){
  __shared__ float X0[KPRE], Y0[KPRE], X1[KPRE], Y1[KPRE], AR[KPRE];
  __shared__ unsigned long long sup[KPRE][8];
  __shared__ unsigned long long keepw[8];
  __shared__ unsigned char vf[KPRE];
  int b = blockIdx.x, tid = threadIdx.x;
  for (int k = tid; k < KPRE; k += 256){
    int src = b*KPRE + k;
    float off = (float)tlabel[src] * 1024.0f;  // 4*PATCH, exact
    float x0 = __fadd_rn(tbox[src*4+0], off), y0 = __fadd_rn(tbox[src*4+1], off);
    float x1 = __fadd_rn(tbox[src*4+2], off), y1 = __fadd_rn(tbox[src*4+3], off);
    X0[k] = x0; Y0[k] = y0; X1[k] = x1; Y1[k] = y1;
    AR[k] = __fmul_rn(fmaxf(__fsub_rn(x1, x0), 0.0f), fmaxf(__fsub_rn(y1, y0), 0.0f));
    vf[k] = (unsigned char)tvalid[src];
  }
  __syncthreads();
  for (int t = tid; t < KPRE*8; t += 256){
    int i = t >> 3, w = t & 7;
    unsigned long long m = 0;
    float ax0 = X0[i], ay0 = Y0[i], ax1 = X1[i], ay1 = Y1[i], aar = AR[i];
    for (int bit = 0; bit < 64; ++bit){
      int j = (w << 6) + bit;
      if (j > i){
        float ltx = fmaxf(ax0, X0[j]), lty = fmaxf(ay0, Y0[j]);
        float rbx = fminf(ax1, X1[j]), rby = fminf(ay1, Y1[j]);
        float ww = fmaxf(__fsub_rn(rbx, ltx), 0.0f), hh = fmaxf(__fsub_rn(rby, lty), 0.0f);
        float inter = __fmul_rn(ww, hh);
        float uni = __fsub_rn(__fadd_rn(aar, AR[j]), inter);
        float iou = __fdiv_rn(inter, fmaxf(uni, 1e-9f));
        if (iou > 0.5f) m |= (1ull << bit);
      }
    }
    sup[i][w] = m;
  }
  __syncthreads();
  if (tid < 64){
    int lane = tid;
    unsigned long long keep = 0;
    if (lane < 8){
      for (int bit = 0; bit < 64; ++bit)
        if (vf[(lane << 6) + bit]) keep |= (1ull << bit);
    }
    for (int i = 0; i < KPRE; ++i){
      unsigned long long kw = __shfl(keep, i >> 6);
      if ((kw >> (i & 63)) & 1ull){
        if (lane < 8) keep &= ~sup[i][lane];
      }
    }
    if (lane < 8) keepw[lane] = keep;
  }
  __syncthreads();
  if (tid < BOXLIM){
    int d = b*BOXLIM + tid;
    sscore[d] = 0.0f; slabel[d] = 0; svalid[d] = 0;
    sbox[d*4+0] = 0.0f; sbox[d*4+1] = 0.0f; sbox[d*4+2] = 0.0f; sbox[d*4+3] = 0.0f;
  }
  __syncthreads();
  int wp[8]; int sum = 0;
#pragma unroll
  for (int w = 0; w < 8; ++w){ wp[w] = sum; sum += __popcll(keepw[w]); }
  for (int r0 = tid; r0 < KPRE; r0 += 256){
    int wi = r0 >> 6, bi = r0 & 63;
    if ((keepw[wi] >> bi) & 1ull){
      unsigned long long below = bi ? (keepw[wi] & ((~0ull) >> (64 - bi))) : 0ull;
      int rank = wp[wi] + __popcll(below);
      if (rank < BOXLIM){
        int src = b*KPRE + r0, d = b*BOXLIM + rank;
        sbox[d*4+0] = tbox[src*4+0]; sbox[d*4+1] = tbox[src*4+1];
        sbox[d*4+2] = tbox[src*4+2]; sbox[d*4+3] = tbox[src*4+3];
        sscore[d] = tscore[src]; slabel[d] = tlabel[src]; svalid[d] = 1;
      }
    }
  }
}

// ---------- K3b: compact valid ROI indices into a dense list ----------

__global__ __launch_bounds__(1024) void k_compact(const int* __restrict__ svalid,
                                                  int* __restrict__ rlist, int* __restrict__ nvalid){
  __shared__ int wcnt[16], woff[16];
  int tid = threadIdx.x;
  int w = tid >> 6, lane = tid & 63;
  int flag = (tid < BIMG*BOXLIM) ? svalid[tid] : 0;
  unsigned long long mask = __ballot(flag != 0);
  if (lane == 0) wcnt[w] = __popcll(mask);
  __syncthreads();
  if (tid == 0){
    int run = 0;
    for (int i = 0; i < 16; ++i){ woff[i] = run; run += wcnt[i]; }
    *nvalid = run;
  }
  __syncthreads();
  if (flag){
    unsigned long long below = lane ? (mask & ((~0ull) >> (64 - lane))) : 0ull;
    rlist[woff[w] + __popcll(below)] = tid;
  }
}

// ---------- K4: merge mask feats to channels-last [8][64][64][480] ----------

__global__ void k_merge(const float* __restrict__ m0, const float* __restrict__ m1,
                        const float* __restrict__ m2, const float* __restrict__ m3,
                        float* __restrict__ merged){
  int t = blockIdx.x*256 + threadIdx.x;
  if (t >= 8*64*64*480) return;
  int c = t % 480; int xy = t / 480;
  int x = xy & 63; int y = (xy >> 6) & 63; int b = xy >> 12;
  float v;
  if (c < 32)       v = m0[(((size_t)b*32  +  c      )*64 +  y      )*64 +  x      ];
  else if (c < 96)  v = m1[(((size_t)b*64  + (c - 32))*32 + (y >> 1))*32 + (x >> 1)];
  else if (c < 224) v = m2[(((size_t)b*128 + (c - 96))*16 + (y >> 2))*16 + (x >> 2)];
  else              v = m3[(((size_t)b*256 + (c - 224))*8 + (y >> 3))*8  + (x >> 3)];
  merged[t] = v;
}

// ---------- K5: fused RoIAlign + conv3x3(480->64) + ReLU + conv1x1(64->1) ----------
// R14 structure with CHANNEL-PAIR PACKING -> v_pk_fma_f32. The fp32 spec peak
// (157 TF) assumes packed fp32; scalar fmaf caps at half. Adjacent channels
// (c,c+1) ride the two halves of a float2: tile is channel-interleaved
// [cp][spatial][2], weights [cp][k][oc][2] (b64 loads), acc2[16] holds
// even/odd-channel PARTIAL sums combined once at the end (2-way channel-sum
// reassociation — same class as R12's validated 4-way split, absmax was 0.0).
// Per-parity chain order (cp ascending, k 0..8, same edge guards) unchanged.
// FMA instruction count and weight-load count halve; taps unchanged.

__global__ __launch_bounds__(1024, 4) void k_maskhead(const float* __restrict__ merged, const float* __restrict__ wT,
    const float* __restrict__ b1, const float* __restrict__ w2, const float* __restrict__ b2,
    const float* __restrict__ sbox, const int* __restrict__ rlist, const int* __restrict__ nvalid,
    float* __restrict__ lm){
  __shared__ float tile[8*576];                   // [cp][(row+1)*16+col][2], rows 0/17 zero halo
  __shared__ __align__(16) float wlds[CCH*576];   // 36 KB = 8 pairs x 9 k x 64 oc x 2
  __shared__ float outp[256];
  int tid = threadIdx.x;
  int oc = tid & 63, row = tid >> 6;      // compute mapping: one row per wave
  int pix = tid & 255, qq = tid >> 8;     // fill mapping: 4 channel-quarters x 256 px
  int pi = pix >> 4, pj = pix & 15;
  float b1v = b1[oc], w2v = w2[oc], b2v = b2[0];
  int NV = *nvalid;

  // zero halo rows once: per cp, floats [0,32) and [544,576)
  for (int i = tid; i < 8*64; i += 1024){
    int cp = i >> 6, q = i & 63;
    tile[cp*576 + ((q < 32) ? q : (512 + q))] = 0.0f;
  }
  __syncthreads();

  for (int it = blockIdx.x; it < NV; it += gridDim.x){
    int r = rlist[it];
    int b = r / 100;
    float bx0 = sbox[r*4+0], by0 = sbox[r*4+1], bx1 = sbox[r*4+2], by1 = sbox[r*4+3];
    float rw = fmaxf(__fsub_rn(bx1, bx0), 1.0f), rh = fmaxf(__fsub_rn(by1, by0), 1.0f);
    float xx = __fadd_rn(bx0, __fdiv_rn(__fmul_rn(__fadd_rn((float)pj, 0.5f), rw), 16.0f));
    float yy = __fadd_rn(by0, __fdiv_rn(__fmul_rn(__fadd_rn((float)pi, 0.5f), rh), 16.0f));
    bool oob = (yy < -1.0f) || (yy > 64.0f) || (xx < -1.0f) || (xx > 64.0f);
    float yc = fminf(fmaxf(yy, 0.0f), 63.0f), xc = fminf(fmaxf(xx, 0.0f), 63.0f);
    int yi0 = (int)floorf(yc), xi0 = (int)floorf(xc);
    int yi1 = min(yi0 + 1, 63), xi1 = min(xi0 + 1, 63);
    float ly = __fsub_rn(yc, (float)yi0), lx = __fsub_rn(xc, (float)xi0);
    float oy = __fsub_rn(1.0f, ly), ox = __fsub_rn(1.0f, lx);
    size_t ib = (size_t)b*64*64*480;
    const float* p00 = merged + ib + (size_t)(yi0*64 + xi0)*480 + qq*4;
    const float* p01 = merged + ib + (size_t)(yi0*64 + xi1)*480 + qq*4;
    const float* p10 = merged + ib + (size_t)(yi1*64 + xi0)*480 + qq*4;
    const float* p11 = merged + ib + (size_t)(yi1*64 + xi1)*480 + qq*4;
    int wpos = (pi + 1)*16 + pj;          // padded interior spatial position
    float2v acc2[16];
#pragma unroll
    for (int j = 0; j < 16; ++j) acc2[j] = (float2v){0.0f, 0.0f};

    for (int cb = 0; cb < 480; cb += CCH){
      __syncthreads();
      // tile stage: thread fills 4 channels (quarter qq) = 2 channel-pairs
      {
        float4 f00 = *(const float4*)(p00 + cb);
        float4 f01 = *(const float4*)(p01 + cb);
        float4 f10 = *(const float4*)(p10 + cb);
        float4 f11 = *(const float4*)(p11 + cb);
        int cp0 = qq*2;
        tile[(cp0+0)*576 + wpos*2 + 0] = bil(f00.x, f01.x, f10.x, f11.x, oy, ly, ox, lx, oob);
        tile[(cp0+0)*576 + wpos*2 + 1] = bil(f00.y, f01.y, f10.y, f11.y, oy, ly, ox, lx, oob);
        tile[(cp0+1)*576 + wpos*2 + 0] = bil(f00.z, f01.z, f10.z, f11.z, oy, ly, ox, lx, oob);
        tile[(cp0+1)*576 + wpos*2 + 1] = bil(f00.w, f01.w, f10.w, f11.w, oy, ly, ox, lx, oob);
      }
      // weight stage: this chunk's 8 pairs x 1152 floats are contiguous at cb*576
      {
        const float4* src = (const float4*)(wT + (size_t)cb*576);
        float4* dst = (float4*)wlds;
        for (int i = tid; i < CCH*144; i += 1024) dst[i] = src[i];
      }
      __syncthreads();
#pragma unroll 1
      for (int cp = 0; cp < 8; ++cp){
        const float* wo = wlds + cp*1152 + (oc << 1);
        float2v W0 = *(const float2v*)(wo + 0*128);
        float2v W1 = *(const float2v*)(wo + 1*128);
        float2v W2 = *(const float2v*)(wo + 2*128);
        float2v W3 = *(const float2v*)(wo + 3*128);
        float2v W4 = *(const float2v*)(wo + 4*128);
        float2v W5 = *(const float2v*)(wo + 5*128);
        float2v W6 = *(const float2v*)(wo + 6*128);
        float2v W7 = *(const float2v*)(wo + 7*128);
        float2v W8 = *(const float2v*)(wo + 8*128);
        const float* tb = tile + cp*576;
        float2v R[16];
        // phase A: padded row 'row' (real row-1) -> k0..2
        {
          const float2v* ra = (const float2v*)(tb + row*32);
#pragma unroll
          for (int j = 0; j < 16; ++j) R[j] = ra[j];
#pragma unroll
          for (int j = 0; j < 16; ++j){
            float2v a = acc2[j];
            if (j > 0)  a = __builtin_elementwise_fma(R[j-1], W0, a);
                        a = __builtin_elementwise_fma(R[j],   W1, a);
            if (j < 15) a = __builtin_elementwise_fma(R[j+1], W2, a);
            acc2[j] = a;
          }
        }
        // phase B: padded row+1 (real row) -> k3..5
        {
          const float2v* ra = (const float2v*)(tb + (row + 1)*32);
#pragma unroll
          for (int j = 0; j < 16; ++j) R[j] = ra[j];
#pragma unroll
          for (int j = 0; j < 16; ++j){
            float2v a = acc2[j];
            if (j > 0)  a = __builtin_elementwise_fma(R[j-1], W3, a);
                        a = __builtin_elementwise_fma(R[j],   W4, a);
            if (j < 15) a = __builtin_elementwise_fma(R[j+1], W5, a);
            acc2[j] = a;
          }
        }
        // phase C: padded row+2 (real row+1) -> k6..8
        {
          const float2v* ra = (const float2v*)(tb + (row + 2)*32);
#pragma unroll
          for (int j = 0; j < 16; ++j) R[j] = ra[j];
#pragma unroll
          for (int j = 0; j < 16; ++j){
            float2v a = acc2[j];
            if (j > 0)  a = __builtin_elementwise_fma(R[j-1], W6, a);
                        a = __builtin_elementwise_fma(R[j],   W7, a);
            if (j < 15) a = __builtin_elementwise_fma(R[j+1], W8, a);
            acc2[j] = a;
          }
        }
      }
    }
#pragma unroll
    for (int j = 0; j < 16; ++j){
      float s = __fadd_rn(acc2[j].x, acc2[j].y);   // combine parity partials
      float hv = fmaxf(__fadd_rn(s, b1v), 0.0f);
      float v = __fmul_rn(hv, w2v);
      v += __shfl_down(v, 32);
      v += __shfl_down(v, 16);
      v += __shfl_down(v, 8);
      v += __shfl_down(v, 4);
      v += __shfl_down(v, 2);
      v += __shfl_down(v, 1);
      if (oc == 0) outp[row*16 + j] = __fadd_rn(v, b2v);
    }
    __syncthreads();
    if (tid < 256) lm[(size_t)r*256 + tid] = outp[tid];
    __syncthreads();
  }
}

// ---------- K6: paste masks + final outputs (mask plane pre-zeroed by memset) ----------

__global__ __launch_bounds__(256) void k_paste(const float* __restrict__ lm, const float* __restrict__ sbox,
    const float* __restrict__ sscore, const int* __restrict__ slabel, const int* __restrict__ svalid,
    float* __restrict__ out0, float* __restrict__ out1, float* __restrict__ out2,
    float* __restrict__ out3, float* __restrict__ out4){
  int r = blockIdx.x, tid = threadIdx.x;
  float* om = out3 + (size_t)r*65536;
  int valid = svalid[r];
  __shared__ unsigned char lmb[256];
  __shared__ int symap[256];
  __shared__ int anyf;
  if (tid == 0) anyf = 0;
  int x0i = 0, y0i = 0, x1i = 0, y1i = 0; int sxv = 0; bool insx = false;
  if (valid){
    float fx0 = sbox[r*4+0], fy0 = sbox[r*4+1], fx1 = sbox[r*4+2], fy1 = sbox[r*4+3];
    x0i = min(max((int)fx0, 0), 255); y0i = min(max((int)fy0, 0), 255);
    x1i = min(max((int)fx1, 0), 255); y1i = min(max((int)fy1, 0), 255);
    int hh = y1i - y0i + 1, wwd = x1i - x0i + 1;
    float logit = lm[(size_t)r*256 + tid];
    float sg = __fdiv_rn(1.0f, __fadd_rn(1.0f, expf(-logit)));
    lmb[tid] = (sg > 0.5f) ? (unsigned char)1 : (unsigned char)0;
    int dy = tid - y0i; symap[tid] = (dy >= 0) ? min((dy*16)/hh, 15) : 0;
    int dx = tid - x0i; sxv = (dx >= 0) ? min((dx*16)/wwd, 15) : 0;
    insx = (tid >= x0i) && (tid <= x1i);
  }
  __syncthreads();
  bool any = false;
  if (valid){
    for (int yy = y0i; yy <= y1i; ++yy){
      int sy = symap[yy];
      bool mm = insx && (lmb[(sy << 4) + sxv] != 0);
      any = any || mm;
      om[yy*256 + tid] = mm ? 1.0f : 0.0f;
    }
  }
  if (any) atomicOr(&anyf, 1);
  __syncthreads();
  if (tid == 0){
    int vout = valid && (anyf != 0);
    out0[r] = vout ? sscore[r] : 0.0f;
    out1[r*4+0] = vout ? sbox[r*4+0] : 0.0f;
    out1[r*4+1] = vout ? sbox[r*4+1] : 0.0f;
    out1[r*4+2] = vout ? sbox[r*4+2] : 0.0f;
    out1[r*4+3] = vout ? sbox[r*4+3] : 0.0f;
    out2[r] = vout ? (float)slabel[r] : 0.0f;
    out4[r] = vout ? 1.0f : 0.0f;
  }
}

// ---------- host ----------

extern "C" void kernel_launch(void* const* d_in, const int* in_sizes, int n_in,
                              void* d_out, int out_size, void* d_ws, size_t ws_size,
                              hipStream_t stream){
  const float* p0 = (const float*)d_in[0];
  const float* p1 = (const float*)d_in[1];
  const float* p2 = (const float*)d_in[2];
  const float* p3 = (const float*)d_in[3];
  const float* m0 = (const float*)d_in[4];
  const float* m1 = (const float*)d_in[5];
  const float* m2 = (const float*)d_in[6];
  const float* m3 = (const float*)d_in[7];
  const float* w1 = (const float*)d_in[8];
  const float* b1 = (const float*)d_in[9];
  const float* w2 = (const float*)d_in[10];
  const float* b2 = (const float*)d_in[11];
  (void)in_sizes; (void)n_in; (void)out_size; (void)ws_size;

  char* ws = (char*)d_ws;
  size_t off = 0;
  auto A = [&](size_t n) -> char* {
    char* p = ws + off;
    off = (off + n + 255) & ~(size_t)255;
    return p;
  };
  float* dbox   = (float*)A((size_t)BIMG*NCAND*4*4);
  float* dscore = (float*)A((size_t)BIMG*NCAND*4);
  int*   dlabel = (int*)A((size_t)BIMG*NCAND*4);
  unsigned long long* dkey = (unsigned long long*)A((size_t)BIMG*NCAND*8);
  float* tbox   = (float*)A((size_t)BIMG*KPRE*4*4);
  float* tscore = (float*)A((size_t)BIMG*KPRE*4);
  int*   tlabel = (int*)A((size_t)BIMG*KPRE*4);
  int*   tvalid = (int*)A((size_t)BIMG*KPRE*4);
  float* sbox   = (float*)A((size_t)BIMG*BOXLIM*4*4);
  float* sscore = (float*)A((size_t)BIMG*BOXLIM*4);
  int*   slabel = (int*)A((size_t)BIMG*BOXLIM*4);
  int*   svalid = (int*)A((size_t)BIMG*BOXLIM*4);
  int*   rlist  = (int*)A((size_t)BIMG*BOXLIM*4);
  int*   nvalid = (int*)A(4);
  float* wT     = (float*)A((size_t)64*480*9*4);
  float* lm     = (float*)A((size_t)800*256*4);
  float* merged = (float*)A((size_t)8*64*64*480*4);

  float* out0 = (float*)d_out;           // scores  [8,100]
  float* out1 = out0 + 800;              // boxes   [8,100,4]
  float* out2 = out1 + 3200;             // labels  [8,100]
  float* out3 = out2 + 800;              // masks   [8,100,256,256]
  float* out4 = out3 + (size_t)8*100*256*256;  // valid [8,100]

  hipMemsetAsync(out3, 0, (size_t)8*100*256*256*4, stream);

  hipLaunchKernelGGL(k_wt,      dim3(1080),  dim3(256),  0, stream, w1, wT);
  hipLaunchKernelGGL(k_decode,  dim3(43),    dim3(256),  0, stream, p0, p1, p2, p3, dbox, dscore, dlabel, dkey);
  hipLaunchKernelGGL(k_merge,   dim3(61440), dim3(256),  0, stream, m0, m1, m2, m3, merged);
  hipLaunchKernelGGL(k_sort,    dim3(8),     dim3(1024), 0, stream, dkey, dbox, dscore, dlabel,
                     tbox, tscore, tlabel, tvalid);
  hipLaunchKernelGGL(k_nms,     dim3(8),     dim3(256),  0, stream, tbox, tscore, tlabel, tvalid,
                     sbox, sscore, slabel, svalid);
  hipLaunchKernelGGL(k_compact, dim3(1),     dim3(1024), 0, stream, svalid, rlist, nvalid);
  hipLaunchKernelGGL(k_maskhead, dim3(800),  dim3(1024), 0, stream, merged, wT, b1, w2, b2,
                     sbox, rlist, nvalid, lm);
  hipLaunchKernelGGL(k_paste,   dim3(800),   dim3(256),  0, stream, lm, sbox, sscore, slabel, svalid,
                     out0, out1, out2, out3, out4);
}